// Round 1
// baseline (959.642 us; speedup 1.0000x reference)
//
#include <hip/hip_runtime.h>
#include <hip/hip_bf16.h>
#include <stdint.h>

#define B_DIM 16384
#define D_DIM 512
#define INV_T (1.0f / 0.07f)

typedef __bf16 bf16x8 __attribute__((ext_vector_type(8)));
typedef float f32x4 __attribute__((ext_vector_type(4)));

typedef const __attribute__((address_space(1))) void* gptr_t;
typedef __attribute__((address_space(3))) void* lptr_t;

__device__ __forceinline__ uint16_t f32_to_bf16_rne(float x) {
  uint32_t b = __builtin_bit_cast(uint32_t, x);
  b += 0x7FFFu + ((b >> 16) & 1u);
  return (uint16_t)(b >> 16);
}

// One wave per row: load 512 fp32, L2-normalize, write 512 bf16.
__global__ __launch_bounds__(256) void normalize_kernel(const float* __restrict__ in,
                                                        uint16_t* __restrict__ out) {
  int wid = threadIdx.x >> 6;
  int lane = threadIdx.x & 63;
  size_t row = (size_t)blockIdx.x * 4 + wid;
  const float* r = in + row * D_DIM;
  float4 v0 = ((const float4*)r)[lane * 2];
  float4 v1 = ((const float4*)r)[lane * 2 + 1];
  float ssq = v0.x * v0.x + v0.y * v0.y + v0.z * v0.z + v0.w * v0.w +
              v1.x * v1.x + v1.y * v1.y + v1.z * v1.z + v1.w * v1.w;
#pragma unroll
  for (int m = 1; m < 64; m <<= 1) ssq += __shfl_xor(ssq, m);
  float scale = 1.0f / fmaxf(sqrtf(ssq), 1e-12f);
  union {
    uint16_t u[8];
    uint4 v;
  } o;
  o.u[0] = f32_to_bf16_rne(v0.x * scale);
  o.u[1] = f32_to_bf16_rne(v0.y * scale);
  o.u[2] = f32_to_bf16_rne(v0.z * scale);
  o.u[3] = f32_to_bf16_rne(v0.w * scale);
  o.u[4] = f32_to_bf16_rne(v1.x * scale);
  o.u[5] = f32_to_bf16_rne(v1.y * scale);
  o.u[6] = f32_to_bf16_rne(v1.z * scale);
  o.u[7] = f32_to_bf16_rne(v1.w * scale);
  ((uint4*)(out + row * D_DIM))[lane] = o.v;
}

// 128x128 tile NT GEMM (logits = Pn . Tn^T / T), fused exp + row/col sums + diag.
__global__ __launch_bounds__(256) void infonce_main(const uint16_t* __restrict__ P,
                                                    const uint16_t* __restrict__ T,
                                                    float* __restrict__ row_sum,
                                                    float* __restrict__ col_sum,
                                                    float* __restrict__ diag) {
  __shared__ __align__(16) uint16_t As[128 * 64];
  __shared__ __align__(16) uint16_t Bs[128 * 64];

  int bid = blockIdx.x;
  // XCD-aware swizzle: 16384 blocks % 8 == 0, bijective.
  int sw = (bid & 7) * 2048 + (bid >> 3);
  int brow = (sw >> 7) << 7;   // 128 block-rows
  int bcol = (sw & 127) << 7;  // 128 block-cols

  int tid = threadIdx.x;
  int lane = tid & 63;
  int wid = tid >> 6;
  int wr = (wid >> 1) * 64;  // wave row offset in tile
  int wc = (wid & 1) * 64;   // wave col offset in tile
  int rlane = lane >> 4;
  int clane = lane & 15;

  f32x4 acc[4][4] = {};

  for (int k0 = 0; k0 < D_DIM; k0 += 64) {
#pragma unroll
    for (int it = 0; it < 4; ++it) {
      int l = it * 256 + tid;
      int r = l >> 3;
      int c = (l & 7) << 3;
      __builtin_amdgcn_global_load_lds(
          (gptr_t)(P + (size_t)(brow + r) * D_DIM + k0 + c),
          (lptr_t)(As + l * 8), 16, 0, 0);
      __builtin_amdgcn_global_load_lds(
          (gptr_t)(T + (size_t)(bcol + r) * D_DIM + k0 + c),
          (lptr_t)(Bs + l * 8), 16, 0, 0);
    }
    __syncthreads();  // compiler drains vmcnt before s_barrier
#pragma unroll
    for (int kk = 0; kk < 64; kk += 32) {
      bf16x8 a[4], b[4];
      int koff = kk + (rlane << 3);
#pragma unroll
      for (int m = 0; m < 4; ++m)
        a[m] = *(const bf16x8*)(As + (wr + m * 16 + clane) * 64 + koff);
#pragma unroll
      for (int n = 0; n < 4; ++n)
        b[n] = *(const bf16x8*)(Bs + (wc + n * 16 + clane) * 64 + koff);
#pragma unroll
      for (int m = 0; m < 4; ++m)
#pragma unroll
        for (int n = 0; n < 4; ++n)
          acc[m][n] = __builtin_amdgcn_mfma_f32_16x16x32_bf16(a[m], b[n], acc[m][n], 0, 0, 0);
    }
    __syncthreads();
  }

  // Epilogue: logit = acc/T; capture diagonal; exponentiate in place.
#pragma unroll
  for (int m = 0; m < 4; ++m)
#pragma unroll
    for (int n = 0; n < 4; ++n)
#pragma unroll
      for (int j = 0; j < 4; ++j) {
        float logit = acc[m][n][j] * INV_T;
        int grow = brow + wr + m * 16 + rlane * 4 + j;
        int gcol = bcol + wc + n * 16 + clane;
        if (grow == gcol) diag[grow] = logit;
        acc[m][n][j] = __expf(logit);
      }

  // Row sums: reduce over n-fragments then across the 16-lane column group.
#pragma unroll
  for (int m = 0; m < 4; ++m)
#pragma unroll
    for (int j = 0; j < 4; ++j) {
      float rs = acc[m][0][j] + acc[m][1][j] + acc[m][2][j] + acc[m][3][j];
      rs += __shfl_xor(rs, 1);
      rs += __shfl_xor(rs, 2);
      rs += __shfl_xor(rs, 4);
      rs += __shfl_xor(rs, 8);
      if (clane == 0) atomicAdd(&row_sum[brow + wr + m * 16 + rlane * 4 + j], rs);
    }

  // Col sums: reduce over m-fragments and regs, then across the 4 row groups.
#pragma unroll
  for (int n = 0; n < 4; ++n) {
    float cs = 0.f;
#pragma unroll
    for (int m = 0; m < 4; ++m)
#pragma unroll
      for (int j = 0; j < 4; ++j) cs += acc[m][n][j];
    cs += __shfl_xor(cs, 16);
    cs += __shfl_xor(cs, 32);
    if (rlane == 0) atomicAdd(&col_sum[bcol + wc + n * 16 + clane], cs);
  }
}

__global__ __launch_bounds__(256) void finalize_kernel(const float* __restrict__ rs,
                                                       const float* __restrict__ cs,
                                                       const float* __restrict__ dg,
                                                       float* __restrict__ out) {
  float s = 0.f;
  for (int i = threadIdx.x; i < B_DIM; i += 256)
    s += 0.5f * (logf(rs[i]) + logf(cs[i])) - dg[i];
#pragma unroll
  for (int m = 1; m < 64; m <<= 1) s += __shfl_xor(s, m);
  __shared__ float red[4];
  if ((threadIdx.x & 63) == 0) red[threadIdx.x >> 6] = s;
  __syncthreads();
  if (threadIdx.x == 0)
    out[0] = (red[0] + red[1] + red[2] + red[3]) * (1.0f / (float)B_DIM);
}

extern "C" void kernel_launch(void* const* d_in, const int* in_sizes, int n_in,
                              void* d_out, int out_size, void* d_ws, size_t ws_size,
                              hipStream_t stream) {
  const float* p = (const float*)d_in[0];
  const float* t = (const float*)d_in[1];
  float* out = (float*)d_out;

  char* ws = (char*)d_ws;
  const size_t embBytes = (size_t)B_DIM * D_DIM * sizeof(uint16_t);  // 16 MB
  uint16_t* Pn = (uint16_t*)ws;
  uint16_t* Tn = (uint16_t*)(ws + embBytes);
  float* row_sum = (float*)(ws + 2 * embBytes);
  float* col_sum = row_sum + B_DIM;
  float* diag = col_sum + B_DIM;

  hipMemsetAsync(row_sum, 0, 2 * (size_t)B_DIM * sizeof(float), stream);
  normalize_kernel<<<B_DIM / 4, 256, 0, stream>>>(p, Pn);
  normalize_kernel<<<B_DIM / 4, 256, 0, stream>>>(t, Tn);
  infonce_main<<<(B_DIM / 128) * (B_DIM / 128), 256, 0, stream>>>(Pn, Tn, row_sum, col_sum, diag);
  finalize_kernel<<<1, 256, 0, stream>>>(row_sum, col_sum, diag, out);
}

// Round 2
// 430.762 us; speedup vs baseline: 2.2278x; 2.2278x over previous
//
#include <hip/hip_runtime.h>
#include <hip/hip_bf16.h>
#include <stdint.h>

#define B_DIM 16384
#define D_DIM 512
#define INV_T (1.0f / 0.07f)

typedef __bf16 bf16x8 __attribute__((ext_vector_type(8)));
typedef float f32x4 __attribute__((ext_vector_type(4)));

typedef const __attribute__((address_space(1))) void* gptr_t;
typedef __attribute__((address_space(3))) void* lptr_t;

__device__ __forceinline__ uint16_t f32_to_bf16_rne(float x) {
  uint32_t b = __builtin_bit_cast(uint32_t, x);
  b += 0x7FFFu + ((b >> 16) & 1u);
  return (uint16_t)(b >> 16);
}

// One wave per row: load 512 fp32, L2-normalize, write 512 bf16.
__global__ __launch_bounds__(256) void normalize_kernel(const float* __restrict__ in,
                                                        uint16_t* __restrict__ out) {
  int wid = threadIdx.x >> 6;
  int lane = threadIdx.x & 63;
  size_t row = (size_t)blockIdx.x * 4 + wid;
  const float* r = in + row * D_DIM;
  float4 v0 = ((const float4*)r)[lane * 2];
  float4 v1 = ((const float4*)r)[lane * 2 + 1];
  float ssq = v0.x * v0.x + v0.y * v0.y + v0.z * v0.z + v0.w * v0.w +
              v1.x * v1.x + v1.y * v1.y + v1.z * v1.z + v1.w * v1.w;
#pragma unroll
  for (int m = 1; m < 64; m <<= 1) ssq += __shfl_xor(ssq, m);
  float scale = 1.0f / fmaxf(sqrtf(ssq), 1e-12f);
  union {
    uint16_t u[8];
    uint4 v;
  } o;
  o.u[0] = f32_to_bf16_rne(v0.x * scale);
  o.u[1] = f32_to_bf16_rne(v0.y * scale);
  o.u[2] = f32_to_bf16_rne(v0.z * scale);
  o.u[3] = f32_to_bf16_rne(v0.w * scale);
  o.u[4] = f32_to_bf16_rne(v1.x * scale);
  o.u[5] = f32_to_bf16_rne(v1.y * scale);
  o.u[6] = f32_to_bf16_rne(v1.z * scale);
  o.u[7] = f32_to_bf16_rne(v1.w * scale);
  ((uint4*)(out + row * D_DIM))[lane] = o.v;
}

// 256x256 tile NT GEMM (logits = Pn . Tn^T / T), 8 waves (2Mx4N), BK=64,
// depth-1 double-buffered prefetch, fused exp + row/col sums + diag.
__global__ __launch_bounds__(512, 2) void infonce_main(const uint16_t* __restrict__ P,
                                                       const uint16_t* __restrict__ T,
                                                       float* __restrict__ row_sum,
                                                       float* __restrict__ col_sum,
                                                       float* __restrict__ diag) {
  __shared__ __align__(16) uint16_t As[2][256][64];  // 64 KB
  __shared__ __align__(16) uint16_t Bs[2][256][64];  // 64 KB

  // XCD-aware rasterization: xcd = bid%8 owns block-rows [xcd*8, xcd*8+8)
  // (A-strip = 2048 rows = 2 MB, L2-resident). Within an XCD, consecutive
  // blocks walk block-rows fastest so concurrent blocks share B-col tiles.
  int bid = blockIdx.x;  // 0..4095
  int xcd = bid & 7;
  int q = bid >> 3;                  // 0..511
  int brow = (xcd * 8 + (q & 7)) << 8;
  int bcol = (q >> 3) << 8;

  int tid = threadIdx.x;
  int lane = tid & 63;
  int wid = tid >> 6;
  int wr = (wid >> 2) * 128;  // wave row offset in tile (2 M-waves)
  int wc = (wid & 3) * 64;    // wave col offset in tile (4 N-waves)
  int rlane = lane >> 4;
  int clane = lane & 15;

  f32x4 acc[8][4] = {};

#define STAGE(buf, k0)                                                              \
  do {                                                                              \
    _Pragma("unroll") for (int it = 0; it < 4; ++it) {                              \
      int l = it * 512 + tid;                                                       \
      int r = l >> 3;                                                               \
      int c = (l & 7) << 3;                                                         \
      __builtin_amdgcn_global_load_lds(                                             \
          (gptr_t)(P + (size_t)(brow + r) * D_DIM + (k0) + c),                      \
          (lptr_t)(&As[buf][0][0] + (size_t)l * 8), 16, 0, 0);                      \
      __builtin_amdgcn_global_load_lds(                                             \
          (gptr_t)(T + (size_t)(bcol + r) * D_DIM + (k0) + c),                      \
          (lptr_t)(&Bs[buf][0][0] + (size_t)l * 8), 16, 0, 0);                      \
    }                                                                               \
  } while (0)

  STAGE(0, 0);
  __syncthreads();  // drains vmcnt: buf0 ready

  for (int t = 0; t < 8; ++t) {
    int cur = t & 1;
    if (t < 7) STAGE(cur ^ 1, (t + 1) * 64);  // prefetch next K-tile, in flight during MFMA
#pragma unroll
    for (int kk = 0; kk < 64; kk += 32) {
      bf16x8 a[8], b[4];
      int koff = kk + (rlane << 3);
#pragma unroll
      for (int m = 0; m < 8; ++m)
        a[m] = *(const bf16x8*)(&As[cur][wr + m * 16 + clane][koff]);
#pragma unroll
      for (int n = 0; n < 4; ++n)
        b[n] = *(const bf16x8*)(&Bs[cur][wc + n * 16 + clane][koff]);
#pragma unroll
      for (int m = 0; m < 8; ++m)
#pragma unroll
        for (int n = 0; n < 4; ++n)
          acc[m][n] = __builtin_amdgcn_mfma_f32_16x16x32_bf16(a[m], b[n], acc[m][n], 0, 0, 0);
    }
    __syncthreads();  // drains lgkm (our reads of buf[cur]) + vmcnt (stage of buf[cur^1])
  }
#undef STAGE

  // Epilogue: logit = acc/T; capture diagonal; exponentiate in place.
#pragma unroll
  for (int m = 0; m < 8; ++m)
#pragma unroll
    for (int n = 0; n < 4; ++n)
#pragma unroll
      for (int j = 0; j < 4; ++j) {
        float logit = acc[m][n][j] * INV_T;
        int grow = brow + wr + m * 16 + rlane * 4 + j;
        int gcol = bcol + wc + n * 16 + clane;
        if (grow == gcol) diag[grow] = logit;
        acc[m][n][j] = __expf(logit);
      }

  // Row sums: reduce over n-fragments then across the 16-lane column group.
#pragma unroll
  for (int m = 0; m < 8; ++m)
#pragma unroll
    for (int j = 0; j < 4; ++j) {
      float rs = acc[m][0][j] + acc[m][1][j] + acc[m][2][j] + acc[m][3][j];
      rs += __shfl_xor(rs, 1);
      rs += __shfl_xor(rs, 2);
      rs += __shfl_xor(rs, 4);
      rs += __shfl_xor(rs, 8);
      if (clane == 0) atomicAdd(&row_sum[brow + wr + m * 16 + rlane * 4 + j], rs);
    }

  // Col sums: reduce over m-fragments and regs, then across the 4 row groups.
#pragma unroll
  for (int n = 0; n < 4; ++n) {
    float cs = 0.f;
#pragma unroll
    for (int m = 0; m < 8; ++m)
#pragma unroll
      for (int j = 0; j < 4; ++j) cs += acc[m][n][j];
    cs += __shfl_xor(cs, 16);
    cs += __shfl_xor(cs, 32);
    if (rlane == 0) atomicAdd(&col_sum[bcol + wc + n * 16 + clane], cs);
  }
}

__global__ __launch_bounds__(256) void finalize_kernel(const float* __restrict__ rs,
                                                       const float* __restrict__ cs,
                                                       const float* __restrict__ dg,
                                                       float* __restrict__ out) {
  float s = 0.f;
  for (int i = threadIdx.x; i < B_DIM; i += 256)
    s += 0.5f * (logf(rs[i]) + logf(cs[i])) - dg[i];
#pragma unroll
  for (int m = 1; m < 64; m <<= 1) s += __shfl_xor(s, m);
  __shared__ float red[4];
  if ((threadIdx.x & 63) == 0) red[threadIdx.x >> 6] = s;
  __syncthreads();
  if (threadIdx.x == 0)
    out[0] = (red[0] + red[1] + red[2] + red[3]) * (1.0f / (float)B_DIM);
}

extern "C" void kernel_launch(void* const* d_in, const int* in_sizes, int n_in,
                              void* d_out, int out_size, void* d_ws, size_t ws_size,
                              hipStream_t stream) {
  const float* p = (const float*)d_in[0];
  const float* t = (const float*)d_in[1];
  float* out = (float*)d_out;

  char* ws = (char*)d_ws;
  const size_t embBytes = (size_t)B_DIM * D_DIM * sizeof(uint16_t);  // 16 MB
  uint16_t* Pn = (uint16_t*)ws;
  uint16_t* Tn = (uint16_t*)(ws + embBytes);
  float* row_sum = (float*)(ws + 2 * embBytes);
  float* col_sum = row_sum + B_DIM;
  float* diag = col_sum + B_DIM;

  hipMemsetAsync(row_sum, 0, 2 * (size_t)B_DIM * sizeof(float), stream);
  normalize_kernel<<<B_DIM / 4, 256, 0, stream>>>(p, Pn);
  normalize_kernel<<<B_DIM / 4, 256, 0, stream>>>(t, Tn);
  infonce_main<<<(B_DIM / 256) * (B_DIM / 256), 512, 0, stream>>>(Pn, Tn, row_sum, col_sum, diag);
  finalize_kernel<<<1, 256, 0, stream>>>(row_sum, col_sum, diag, out);
}

// Round 3
// 403.070 us; speedup vs baseline: 2.3808x; 1.0687x over previous
//
#include <hip/hip_runtime.h>
#include <hip/hip_bf16.h>
#include <stdint.h>

#define B_DIM 16384
#define D_DIM 512
#define INV_T (1.0f / 0.07f)

typedef __bf16 bf16x8 __attribute__((ext_vector_type(8)));
typedef float f32x4 __attribute__((ext_vector_type(4)));

typedef const __attribute__((address_space(1))) void* gptr_t;
typedef __attribute__((address_space(3))) void* lptr_t;

__device__ __forceinline__ uint16_t f32_to_bf16_rne(float x) {
  uint32_t b = __builtin_bit_cast(uint32_t, x);
  b += 0x7FFFu + ((b >> 16) & 1u);
  return (uint16_t)(b >> 16);
}

// One wave per row: load 512 fp32, L2-normalize, write 512 bf16.
__global__ __launch_bounds__(256) void normalize_kernel(const float* __restrict__ in,
                                                        uint16_t* __restrict__ out) {
  int wid = threadIdx.x >> 6;
  int lane = threadIdx.x & 63;
  size_t row = (size_t)blockIdx.x * 4 + wid;
  const float* r = in + row * D_DIM;
  float4 v0 = ((const float4*)r)[lane * 2];
  float4 v1 = ((const float4*)r)[lane * 2 + 1];
  float ssq = v0.x * v0.x + v0.y * v0.y + v0.z * v0.z + v0.w * v0.w +
              v1.x * v1.x + v1.y * v1.y + v1.z * v1.z + v1.w * v1.w;
#pragma unroll
  for (int m = 1; m < 64; m <<= 1) ssq += __shfl_xor(ssq, m);
  float scale = 1.0f / fmaxf(sqrtf(ssq), 1e-12f);
  union {
    uint16_t u[8];
    uint4 v;
  } o;
  o.u[0] = f32_to_bf16_rne(v0.x * scale);
  o.u[1] = f32_to_bf16_rne(v0.y * scale);
  o.u[2] = f32_to_bf16_rne(v0.z * scale);
  o.u[3] = f32_to_bf16_rne(v0.w * scale);
  o.u[4] = f32_to_bf16_rne(v1.x * scale);
  o.u[5] = f32_to_bf16_rne(v1.y * scale);
  o.u[6] = f32_to_bf16_rne(v1.z * scale);
  o.u[7] = f32_to_bf16_rne(v1.w * scale);
  ((uint4*)(out + row * D_DIM))[lane] = o.v;
}

// 256x256 tile NT GEMM, 8 waves (2Mx4N), BK=64 split into two K-halves.
// 4-phase/K-tile schedule, half-tile-granular staging pipeline with counted
// vmcnt (never 0 in main loop), conflict-free [256][32] LDS layout, setprio
// around MFMA clusters. Fused exp + row/col sums + diag.
__global__ __launch_bounds__(512, 2) void infonce_main(const uint16_t* __restrict__ P,
                                                       const uint16_t* __restrict__ T,
                                                       float* __restrict__ row_sum,
                                                       float* __restrict__ col_sum,
                                                       float* __restrict__ diag) {
  // [buf][kh][row][col32]: row stride 64 B -> ds_read_b128 bank-group
  // (4*clane+rlane)&7: each 4-bank group hit exactly 8x/wave = conflict-free.
  // Each [256][32] K-half is a contiguous 16 KB block = linear gload_lds dest.
  __shared__ __align__(16) uint16_t As[2][2][256][32];  // 64 KB
  __shared__ __align__(16) uint16_t Bs[2][2][256][32];  // 64 KB

  int bid = blockIdx.x;
  int xcd = bid & 7;
  int q = bid >> 3;
  int brow = (xcd * 8 + (q & 7)) << 8;
  int bcol = (q >> 3) << 8;

  int tid = threadIdx.x;
  int lane = tid & 63;
  int wid = tid >> 6;
  int wr = (wid >> 2) * 128;  // 2 M-waves
  int wc = (wid & 3) * 64;    // 4 N-waves
  int rlane = lane >> 4;
  int clane = lane & 15;

  f32x4 acc[8][4] = {};

  // Stage one K-half (16 KB): 2 x global_load_lds(16B) per thread, linear dest.
#define STAGE_HALF(dst, src, rbase, buf, kh, kt)                              \
  do {                                                                        \
    _Pragma("unroll") for (int it = 0; it < 2; ++it) {                        \
      int l = it * 512 + tid;                                                 \
      __builtin_amdgcn_global_load_lds(                                       \
          (gptr_t)(src + (size_t)(rbase + (l >> 2)) * D_DIM + (kt) * 64 +     \
                   (kh) * 32 + (l & 3) * 8),                                  \
          (lptr_t)(&dst[buf][kh][0][0] + (size_t)l * 8), 16, 0, 0);           \
    }                                                                         \
  } while (0)

  // Phase: ds-read fragments, issue stage, optional counted vmcnt, barrier,
  // prio-boosted 16-MFMA cluster, barrier.
#define PHASE(kh, mh, READ_B, STAGE_STMT, VMCNT_STMT)                               \
  do {                                                                              \
    bf16x8 a[4];                                                                    \
    _Pragma("unroll") for (int mq = 0; mq < 4; ++mq)                                \
      a[mq] = *(const bf16x8*)(&As[cur][kh][wr + (mh) * 64 + mq * 16 + clane]       \
                                  [rlane * 8]);                                     \
    if (READ_B) {                                                                   \
      _Pragma("unroll") for (int n = 0; n < 4; ++n)                                 \
        b[n] = *(const bf16x8*)(&Bs[cur][kh][wc + n * 16 + clane][rlane * 8]);      \
    }                                                                               \
    STAGE_STMT;                                                                     \
    VMCNT_STMT;                                                                     \
    __builtin_amdgcn_s_barrier();                                                   \
    __builtin_amdgcn_sched_barrier(0);                                              \
    __builtin_amdgcn_s_setprio(1);                                                  \
    _Pragma("unroll") for (int mq = 0; mq < 4; ++mq)                                \
      _Pragma("unroll") for (int n = 0; n < 4; ++n)                                 \
        acc[(mh) * 4 + mq][n] = __builtin_amdgcn_mfma_f32_16x16x32_bf16(            \
            a[mq], b[n], acc[(mh) * 4 + mq][n], 0, 0, 0);                           \
    __builtin_amdgcn_s_setprio(0);                                                  \
    __builtin_amdgcn_s_barrier();                                                   \
    __builtin_amdgcn_sched_barrier(0);                                              \
  } while (0)

  // Prologue: issue first 6 half-tiles; ensure Ak0(0), Bk0(0) landed.
  STAGE_HALF(As, P, brow, 0, 0, 0);
  STAGE_HALF(Bs, T, bcol, 0, 0, 0);
  STAGE_HALF(As, P, brow, 0, 1, 0);
  STAGE_HALF(Bs, T, bcol, 0, 1, 0);
  STAGE_HALF(As, P, brow, 1, 0, 1);
  STAGE_HALF(Bs, T, bcol, 1, 0, 1);
  asm volatile("s_waitcnt vmcnt(8)" ::: "memory");
  __builtin_amdgcn_s_barrier();
  __builtin_amdgcn_sched_barrier(0);

#pragma unroll
  for (int t = 0; t < 8; ++t) {
    const int cur = t & 1;
    bf16x8 b[4];
    // Stage ledger (issue during tile t): p1: Ak1(t+1), p2: Bk1(t+1),
    // p3: Ak0(t+2), p4: Bk0(t+2). Each target's last reader completed one
    // full phase before the issue; vmcnt(6) at p2/p4 lands every half one
    // phase before its first read. Epilogue tightens: t=6 p4 vmcnt(4),
    // t=7 p2 vmcnt(0).
    PHASE(0, 0, 1,
          { if (t < 7) STAGE_HALF(As, P, brow, (t + 1) & 1, 1, t + 1); }, );
    PHASE(0, 1, 0,
          { if (t < 7) STAGE_HALF(Bs, T, bcol, (t + 1) & 1, 1, t + 1); },
          {
            if (t < 7) asm volatile("s_waitcnt vmcnt(6)" ::: "memory");
            else       asm volatile("s_waitcnt vmcnt(0)" ::: "memory");
          });
    PHASE(1, 0, 1,
          { if (t < 6) STAGE_HALF(As, P, brow, t & 1, 0, t + 2); }, );
    PHASE(1, 1, 0,
          { if (t < 6) STAGE_HALF(Bs, T, bcol, t & 1, 0, t + 2); },
          {
            if (t < 6)      asm volatile("s_waitcnt vmcnt(6)" ::: "memory");
            else if (t == 6) asm volatile("s_waitcnt vmcnt(4)" ::: "memory");
          });
  }
#undef PHASE
#undef STAGE_HALF

  // Epilogue: logit = acc/T; capture diagonal; exponentiate in place.
#pragma unroll
  for (int m = 0; m < 8; ++m)
#pragma unroll
    for (int n = 0; n < 4; ++n)
#pragma unroll
      for (int j = 0; j < 4; ++j) {
        float logit = acc[m][n][j] * INV_T;
        int grow = brow + wr + m * 16 + rlane * 4 + j;
        int gcol = bcol + wc + n * 16 + clane;
        if (grow == gcol) diag[grow] = logit;
        acc[m][n][j] = __expf(logit);
      }

  // Row sums: reduce over n-fragments then across the 16-lane column group.
#pragma unroll
  for (int m = 0; m < 8; ++m)
#pragma unroll
    for (int j = 0; j < 4; ++j) {
      float rs = acc[m][0][j] + acc[m][1][j] + acc[m][2][j] + acc[m][3][j];
      rs += __shfl_xor(rs, 1);
      rs += __shfl_xor(rs, 2);
      rs += __shfl_xor(rs, 4);
      rs += __shfl_xor(rs, 8);
      if (clane == 0) atomicAdd(&row_sum[brow + wr + m * 16 + rlane * 4 + j], rs);
    }

  // Col sums: reduce over m-fragments and regs, then across the 4 row groups.
#pragma unroll
  for (int n = 0; n < 4; ++n) {
    float cs = 0.f;
#pragma unroll
    for (int m = 0; m < 8; ++m)
#pragma unroll
      for (int j = 0; j < 4; ++j) cs += acc[m][n][j];
    cs += __shfl_xor(cs, 16);
    cs += __shfl_xor(cs, 32);
    if (rlane == 0) atomicAdd(&col_sum[bcol + wc + n * 16 + clane], cs);
  }
}

__global__ __launch_bounds__(256) void finalize_kernel(const float* __restrict__ rs,
                                                       const float* __restrict__ cs,
                                                       const float* __restrict__ dg,
                                                       float* __restrict__ out) {
  float s = 0.f;
  for (int i = threadIdx.x; i < B_DIM; i += 256)
    s += 0.5f * (logf(rs[i]) + logf(cs[i])) - dg[i];
#pragma unroll
  for (int m = 1; m < 64; m <<= 1) s += __shfl_xor(s, m);
  __shared__ float red[4];
  if ((threadIdx.x & 63) == 0) red[threadIdx.x >> 6] = s;
  __syncthreads();
  if (threadIdx.x == 0)
    out[0] = (red[0] + red[1] + red[2] + red[3]) * (1.0f / (float)B_DIM);
}

extern "C" void kernel_launch(void* const* d_in, const int* in_sizes, int n_in,
                              void* d_out, int out_size, void* d_ws, size_t ws_size,
                              hipStream_t stream) {
  const float* p = (const float*)d_in[0];
  const float* t = (const float*)d_in[1];
  float* out = (float*)d_out;

  char* ws = (char*)d_ws;
  const size_t embBytes = (size_t)B_DIM * D_DIM * sizeof(uint16_t);  // 16 MB
  uint16_t* Pn = (uint16_t*)ws;
  uint16_t* Tn = (uint16_t*)(ws + embBytes);
  float* row_sum = (float*)(ws + 2 * embBytes);
  float* col_sum = row_sum + B_DIM;
  float* diag = col_sum + B_DIM;

  hipMemsetAsync(row_sum, 0, 2 * (size_t)B_DIM * sizeof(float), stream);
  normalize_kernel<<<B_DIM / 4, 256, 0, stream>>>(p, Pn);
  normalize_kernel<<<B_DIM / 4, 256, 0, stream>>>(t, Tn);
  infonce_main<<<(B_DIM / 256) * (B_DIM / 256), 512, 0, stream>>>(Pn, Tn, row_sum, col_sum, diag);
  finalize_kernel<<<1, 256, 0, stream>>>(row_sum, col_sum, diag, out);
}

// Round 4
// 400.314 us; speedup vs baseline: 2.3972x; 1.0069x over previous
//
#include <hip/hip_runtime.h>
#include <hip/hip_bf16.h>
#include <stdint.h>

#define B_DIM 16384
#define D_DIM 512
#define INV_T (1.0f / 0.07f)

typedef __bf16 bf16x8 __attribute__((ext_vector_type(8)));
typedef float f32x4 __attribute__((ext_vector_type(4)));

typedef const __attribute__((address_space(1))) void* gptr_t;
typedef __attribute__((address_space(3))) void* lptr_t;

__device__ __forceinline__ uint16_t f32_to_bf16_rne(float x) {
  uint32_t b = __builtin_bit_cast(uint32_t, x);
  b += 0x7FFFu + ((b >> 16) & 1u);
  return (uint16_t)(b >> 16);
}

// One wave per row: load 512 fp32, L2-normalize, write 512 bf16.
__global__ __launch_bounds__(256) void normalize_kernel(const float* __restrict__ in,
                                                        uint16_t* __restrict__ out) {
  int wid = threadIdx.x >> 6;
  int lane = threadIdx.x & 63;
  size_t row = (size_t)blockIdx.x * 4 + wid;
  const float* r = in + row * D_DIM;
  float4 v0 = ((const float4*)r)[lane * 2];
  float4 v1 = ((const float4*)r)[lane * 2 + 1];
  float ssq = v0.x * v0.x + v0.y * v0.y + v0.z * v0.z + v0.w * v0.w +
              v1.x * v1.x + v1.y * v1.y + v1.z * v1.z + v1.w * v1.w;
#pragma unroll
  for (int m = 1; m < 64; m <<= 1) ssq += __shfl_xor(ssq, m);
  float scale = 1.0f / fmaxf(sqrtf(ssq), 1e-12f);
  union {
    uint16_t u[8];
    uint4 v;
  } o;
  o.u[0] = f32_to_bf16_rne(v0.x * scale);
  o.u[1] = f32_to_bf16_rne(v0.y * scale);
  o.u[2] = f32_to_bf16_rne(v0.z * scale);
  o.u[3] = f32_to_bf16_rne(v0.w * scale);
  o.u[4] = f32_to_bf16_rne(v1.x * scale);
  o.u[5] = f32_to_bf16_rne(v1.y * scale);
  o.u[6] = f32_to_bf16_rne(v1.z * scale);
  o.u[7] = f32_to_bf16_rne(v1.w * scale);
  ((uint4*)(out + row * D_DIM))[lane] = o.v;
}

// 256x256 tile NT GEMM, 8 waves (2Mx4N), BK=64 split into two K-halves.
// 4-phase/K-tile schedule, half-tile-granular staging pipeline with counted
// vmcnt (never 0 in main loop), conflict-free [256][32] LDS layout, setprio
// around MFMA clusters. NO sched_barrier pins (m141: order-pinning defeats
// the compiler scheduler). Fused exp + row/col sums + diag.
__global__ __launch_bounds__(512, 2) void infonce_main(const uint16_t* __restrict__ P,
                                                       const uint16_t* __restrict__ T,
                                                       float* __restrict__ row_sum,
                                                       float* __restrict__ col_sum,
                                                       float* __restrict__ diag) {
  // [buf][kh][row][col32]: row stride 64 B -> ds_read_b128 bank-group
  // (4*clane+rlane)&7: each 4-bank group hit exactly 8x/wave = conflict-free.
  // Each [256][32] K-half is a contiguous 16 KB block = linear gload_lds dest.
  __shared__ __align__(16) uint16_t As[2][2][256][32];  // 64 KB
  __shared__ __align__(16) uint16_t Bs[2][2][256][32];  // 64 KB

  int bid = blockIdx.x;
  int xcd = bid & 7;
  int q = bid >> 3;
  int brow = (xcd * 8 + (q & 7)) << 8;
  int bcol = (q >> 3) << 8;

  int tid = threadIdx.x;
  int lane = tid & 63;
  int wid = tid >> 6;
  int wr = (wid >> 2) * 128;  // 2 M-waves
  int wc = (wid & 3) * 64;    // 4 N-waves
  int rlane = lane >> 4;
  int clane = lane & 15;

  f32x4 acc[8][4] = {};

  // Stage one K-half (16 KB): 2 x global_load_lds(16B) per thread, linear dest.
#define STAGE_HALF(dst, src, rbase, buf, kh, kt)                              \
  do {                                                                        \
    _Pragma("unroll") for (int it = 0; it < 2; ++it) {                        \
      int l = it * 512 + tid;                                                 \
      __builtin_amdgcn_global_load_lds(                                       \
          (gptr_t)(src + (size_t)(rbase + (l >> 2)) * D_DIM + (kt) * 64 +     \
                   (kh) * 32 + (l & 3) * 8),                                  \
          (lptr_t)(&dst[buf][kh][0][0] + (size_t)l * 8), 16, 0, 0);           \
    }                                                                         \
  } while (0)

  // Phase: ds-read fragments, issue stage, optional counted vmcnt, barrier,
  // prio-boosted 16-MFMA cluster, barrier.
#define PHASE(kh, mh, READ_B, STAGE_STMT, VMCNT_STMT)                               \
  do {                                                                              \
    bf16x8 a[4];                                                                    \
    _Pragma("unroll") for (int mq = 0; mq < 4; ++mq)                                \
      a[mq] = *(const bf16x8*)(&As[cur][kh][wr + (mh) * 64 + mq * 16 + clane]       \
                                  [rlane * 8]);                                     \
    if (READ_B) {                                                                   \
      _Pragma("unroll") for (int n = 0; n < 4; ++n)                                 \
        b[n] = *(const bf16x8*)(&Bs[cur][kh][wc + n * 16 + clane][rlane * 8]);      \
    }                                                                               \
    STAGE_STMT;                                                                     \
    VMCNT_STMT;                                                                     \
    __builtin_amdgcn_s_barrier();                                                   \
    __builtin_amdgcn_s_setprio(1);                                                  \
    _Pragma("unroll") for (int mq = 0; mq < 4; ++mq)                                \
      _Pragma("unroll") for (int n = 0; n < 4; ++n)                                 \
        acc[(mh) * 4 + mq][n] = __builtin_amdgcn_mfma_f32_16x16x32_bf16(            \
            a[mq], b[n], acc[(mh) * 4 + mq][n], 0, 0, 0);                           \
    __builtin_amdgcn_s_setprio(0);                                                  \
    __builtin_amdgcn_s_barrier();                                                   \
  } while (0)

  // Prologue: issue first 6 half-tiles; ensure Ak0(0), Bk0(0) landed.
  STAGE_HALF(As, P, brow, 0, 0, 0);
  STAGE_HALF(Bs, T, bcol, 0, 0, 0);
  STAGE_HALF(As, P, brow, 0, 1, 0);
  STAGE_HALF(Bs, T, bcol, 0, 1, 0);
  STAGE_HALF(As, P, brow, 1, 0, 1);
  STAGE_HALF(Bs, T, bcol, 1, 0, 1);
  asm volatile("s_waitcnt vmcnt(8)" ::: "memory");
  __builtin_amdgcn_s_barrier();

#pragma unroll
  for (int t = 0; t < 8; ++t) {
    const int cur = t & 1;
    bf16x8 b[4];
    // Stage ledger (issue during tile t): p1: Ak1(t+1), p2: Bk1(t+1),
    // p3: Ak0(t+2), p4: Bk0(t+2). Each target's last reader completed one
    // full phase before the issue; vmcnt(6) at p2/p4 lands every half one
    // phase before its first read. Epilogue tightens: t=6 p4 vmcnt(4),
    // t=7 p2 vmcnt(0).
    PHASE(0, 0, 1,
          { if (t < 7) STAGE_HALF(As, P, brow, (t + 1) & 1, 1, t + 1); }, );
    PHASE(0, 1, 0,
          { if (t < 7) STAGE_HALF(Bs, T, bcol, (t + 1) & 1, 1, t + 1); },
          {
            if (t < 7) asm volatile("s_waitcnt vmcnt(6)" ::: "memory");
            else       asm volatile("s_waitcnt vmcnt(0)" ::: "memory");
          });
    PHASE(1, 0, 1,
          { if (t < 6) STAGE_HALF(As, P, brow, t & 1, 0, t + 2); }, );
    PHASE(1, 1, 0,
          { if (t < 6) STAGE_HALF(Bs, T, bcol, t & 1, 0, t + 2); },
          {
            if (t < 6)      asm volatile("s_waitcnt vmcnt(6)" ::: "memory");
            else if (t == 6) asm volatile("s_waitcnt vmcnt(4)" ::: "memory");
          });
  }
#undef PHASE
#undef STAGE_HALF

  // Epilogue: logit = acc/T; capture diagonal; exponentiate in place.
#pragma unroll
  for (int m = 0; m < 8; ++m)
#pragma unroll
    for (int n = 0; n < 4; ++n)
#pragma unroll
      for (int j = 0; j < 4; ++j) {
        float logit = acc[m][n][j] * INV_T;
        int grow = brow + wr + m * 16 + rlane * 4 + j;
        int gcol = bcol + wc + n * 16 + clane;
        if (grow == gcol) diag[grow] = logit;
        acc[m][n][j] = __expf(logit);
      }

  // Row sums: reduce over n-fragments then across the 16-lane column group.
#pragma unroll
  for (int m = 0; m < 8; ++m)
#pragma unroll
    for (int j = 0; j < 4; ++j) {
      float rs = acc[m][0][j] + acc[m][1][j] + acc[m][2][j] + acc[m][3][j];
      rs += __shfl_xor(rs, 1);
      rs += __shfl_xor(rs, 2);
      rs += __shfl_xor(rs, 4);
      rs += __shfl_xor(rs, 8);
      if (clane == 0) atomicAdd(&row_sum[brow + wr + m * 16 + rlane * 4 + j], rs);
    }

  // Col sums: reduce over m-fragments and regs, then across the 4 row groups.
#pragma unroll
  for (int n = 0; n < 4; ++n) {
    float cs = 0.f;
#pragma unroll
    for (int m = 0; m < 8; ++m)
#pragma unroll
      for (int j = 0; j < 4; ++j) cs += acc[m][n][j];
    cs += __shfl_xor(cs, 16);
    cs += __shfl_xor(cs, 32);
    if (rlane == 0) atomicAdd(&col_sum[bcol + wc + n * 16 + clane], cs);
  }
}

__global__ __launch_bounds__(256) void finalize_kernel(const float* __restrict__ rs,
                                                       const float* __restrict__ cs,
                                                       const float* __restrict__ dg,
                                                       float* __restrict__ out) {
  float s = 0.f;
  for (int i = threadIdx.x; i < B_DIM; i += 256)
    s += 0.5f * (logf(rs[i]) + logf(cs[i])) - dg[i];
#pragma unroll
  for (int m = 1; m < 64; m <<= 1) s += __shfl_xor(s, m);
  __shared__ float red[4];
  if ((threadIdx.x & 63) == 0) red[threadIdx.x >> 6] = s;
  __syncthreads();
  if (threadIdx.x == 0)
    out[0] = (red[0] + red[1] + red[2] + red[3]) * (1.0f / (float)B_DIM);
}

extern "C" void kernel_launch(void* const* d_in, const int* in_sizes, int n_in,
                              void* d_out, int out_size, void* d_ws, size_t ws_size,
                              hipStream_t stream) {
  const float* p = (const float*)d_in[0];
  const float* t = (const float*)d_in[1];
  float* out = (float*)d_out;

  char* ws = (char*)d_ws;
  const size_t embBytes = (size_t)B_DIM * D_DIM * sizeof(uint16_t);  // 16 MB
  uint16_t* Pn = (uint16_t*)ws;
  uint16_t* Tn = (uint16_t*)(ws + embBytes);
  float* row_sum = (float*)(ws + 2 * embBytes);
  float* col_sum = row_sum + B_DIM;
  float* diag = col_sum + B_DIM;

  hipMemsetAsync(row_sum, 0, 2 * (size_t)B_DIM * sizeof(float), stream);
  normalize_kernel<<<B_DIM / 4, 256, 0, stream>>>(p, Pn);
  normalize_kernel<<<B_DIM / 4, 256, 0, stream>>>(t, Tn);
  infonce_main<<<(B_DIM / 256) * (B_DIM / 256), 512, 0, stream>>>(Pn, Tn, row_sum, col_sum, diag);
  finalize_kernel<<<1, 256, 0, stream>>>(row_sum, col_sum, diag, out);
}